// Round 5
// baseline (32.293 us; speedup 1.0000x reference)
//
#include <hip/hip_runtime.h>
#include <hip/hip_bf16.h>

// Two-kernel MLPRegressor, load-balanced:
//  K1 pool_tiles: block = (sample b, half h) -> 4 waves, each one 64-row tile.
//     Computes: 95-bin histogram (4 big cat tables, per-wave LDS atomics),
//     packed binary ones-counts (3 card-2 tables), cont ReLU sums (quad layout).
//     Writes partials NON-atomically to slot bb = 2*b+h in d_ws.
//     Blocks with len <= h*256 exit immediately; K2 never reads their slot.
//  K2 head: wave = sample (4 samples / 256-thr block). Rebuilds bin weights,
//     does the 101-row weighted embedding matvec, cont mean, W1+relu, W2+relu.
//
// Slot layout (stride 176 ints = 704 B):
//   int   [0..94]   hist bins (t3:0-10, t4:11-29, t5:30-60, t6:61-94)
//   int   [95..97]  ones-counts for binary tables 0..2
//   float [104..167] cont ReLU sums (dims 0..63)

#define CARD3 11
#define CARD4 19
#define CARD5 31
#define CARD6 34
#define SLOT_STRIDE 176

__global__ __launch_bounds__(256) void pool_tiles(
    const float* __restrict__ cont_x,   // [B,S,5]
    const int*   __restrict__ cat_x,    // [B,S,7]
    const int*   __restrict__ length,   // [B]
    const float* __restrict__ W_cont,   // [5,64]
    const float* __restrict__ b_cont,   // [64]
    int*         __restrict__ ws_i,     // slots
    int S)
{
    constexpr int HOFF[4] = {0, 11, 30, 61};

    __shared__ int hist[4][96];
    __shared__ int bc_s[4];
    __shared__ __align__(16) float4 pc4[4][16];

    const int bb   = blockIdx.x;
    const int b    = bb >> 1;
    const int half = bb & 1;
    const int len  = length[b];
    const int base0 = half * 256;
    if (len <= base0) return;

    const int tid = threadIdx.x;
    const int g   = tid >> 6;
    const int l   = tid & 63;
    const int rg  = l >> 4;
    const int q   = l & 15;

    {
        int* hz = &hist[0][0];
        for (int i = tid; i < 4 * 96; i += 256) hz[i] = 0;
    }

    const float4* Wc4 = (const float4*)W_cont;
    float4 wc0  = Wc4[0 * 16 + q];
    float4 wc1  = Wc4[1 * 16 + q];
    float4 wc2  = Wc4[2 * 16 + q];
    float4 wc3  = Wc4[3 * 16 + q];
    float4 wc4v = Wc4[4 * 16 + q];
    float4 bc4  = ((const float4*)b_cont)[q];

    __syncthreads();   // hist zeroed

    const int base = base0 + g * 64;
    const int rows = min(64, len - base);   // may be <= 0 for this wave

    int    c1pack   = 0;
    float4 acc_cont = {0.f, 0.f, 0.f, 0.f};

    if (rows > 0) {
        const int*   cp0 = cat_x  + ((size_t)b * S + base) * 7;
        const float* xp0 = cont_x + ((size_t)b * S + base) * 5;

        int   id[7];
        float xv[5];
        if (l < rows) {
            const int* cp = cp0 + l * 7;
#pragma unroll
            for (int t = 0; t < 7; ++t) id[t] = cp[t];
            const float* xp = xp0 + l * 5;
#pragma unroll
            for (int j = 0; j < 5; ++j) xv[j] = xp[j];
        } else {
#pragma unroll
            for (int t = 0; t < 7; ++t) id[t] = 0;
#pragma unroll
            for (int j = 0; j < 5; ++j) xv[j] = 0.f;
        }

        if (l < rows) {
            c1pack = id[0] + (id[1] << 8) + (id[2] << 16);
            atomicAdd(&hist[g][HOFF[0] + id[3]], 1);
            atomicAdd(&hist[g][HOFF[1] + id[4]], 1);
            atomicAdd(&hist[g][HOFF[2] + id[5]], 1);
            atomicAdd(&hist[g][HOFF[3] + id[6]], 1);
        }

        const int quads = (rows + 3) >> 2;
#pragma unroll 4
        for (int r4 = 0; r4 < quads; ++r4) {
            const int rr = r4 * 4 + rg;

            float bx0 = __shfl(xv[0], rr);
            float bx1 = __shfl(xv[1], rr);
            float bx2 = __shfl(xv[2], rr);
            float bx3 = __shfl(xv[3], rr);
            float bx4 = __shfl(xv[4], rr);

            float4 ch = bc4;
            ch.x = fmaf(bx0, wc0.x, ch.x); ch.y = fmaf(bx0, wc0.y, ch.y);
            ch.z = fmaf(bx0, wc0.z, ch.z); ch.w = fmaf(bx0, wc0.w, ch.w);
            ch.x = fmaf(bx1, wc1.x, ch.x); ch.y = fmaf(bx1, wc1.y, ch.y);
            ch.z = fmaf(bx1, wc1.z, ch.z); ch.w = fmaf(bx1, wc1.w, ch.w);
            ch.x = fmaf(bx2, wc2.x, ch.x); ch.y = fmaf(bx2, wc2.y, ch.y);
            ch.z = fmaf(bx2, wc2.z, ch.z); ch.w = fmaf(bx2, wc2.w, ch.w);
            ch.x = fmaf(bx3, wc3.x, ch.x); ch.y = fmaf(bx3, wc3.y, ch.y);
            ch.z = fmaf(bx3, wc3.z, ch.z); ch.w = fmaf(bx3, wc3.w, ch.w);
            ch.x = fmaf(bx4, wc4v.x, ch.x); ch.y = fmaf(bx4, wc4v.y, ch.y);
            ch.z = fmaf(bx4, wc4v.z, ch.z); ch.w = fmaf(bx4, wc4v.w, ch.w);

            if (rr < rows) {
                acc_cont.x += fmaxf(ch.x, 0.f);
                acc_cont.y += fmaxf(ch.y, 0.f);
                acc_cont.z += fmaxf(ch.z, 0.f);
                acc_cont.w += fmaxf(ch.w, 0.f);
            }
        }
    }

    // reduce packed binary counts across lanes (fields < 256)
#pragma unroll
    for (int off = 1; off <= 32; off <<= 1) c1pack += __shfl_xor(c1pack, off);
    if (l == 0) bc_s[g] = c1pack;

    // cont reduce over rg
#pragma unroll
    for (int off = 16; off <= 32; off <<= 1) {
        acc_cont.x += __shfl_xor(acc_cont.x, off);
        acc_cont.y += __shfl_xor(acc_cont.y, off);
        acc_cont.z += __shfl_xor(acc_cont.z, off);
        acc_cont.w += __shfl_xor(acc_cont.w, off);
    }
    if (rg == 0) pc4[g][q] = acc_cont;

    __syncthreads();

    int*   slot   = ws_i + (size_t)bb * SLOT_STRIDE;
    float* slot_f = (float*)slot;

    if (tid < 95) {
        slot[tid] = hist[0][tid] + hist[1][tid] + hist[2][tid] + hist[3][tid];
    }
    if (tid >= 96 && tid < 99) {
        const int j = tid - 96;
        const int c1 = ((bc_s[0] >> (8 * j)) & 0xFF) + ((bc_s[1] >> (8 * j)) & 0xFF)
                     + ((bc_s[2] >> (8 * j)) & 0xFF) + ((bc_s[3] >> (8 * j)) & 0xFF);
        slot[95 + j] = c1;
    }
    if (tid >= 128 && tid < 192) {
        const int d = tid - 128;
        const float* pf = (const float*)pc4;   // [4][64]
        slot_f[104 + d] = pf[d] + pf[64 + d] + pf[128 + d] + pf[192 + d];
    }
}

__global__ __launch_bounds__(256) void head_kernel(
    const int*   __restrict__ ws_i,
    const int*   __restrict__ length,   // [B]
    const float* __restrict__ e0, const float* __restrict__ e1,
    const float* __restrict__ e2, const float* __restrict__ e3,
    const float* __restrict__ e4, const float* __restrict__ e5,
    const float* __restrict__ e6,
    const float* __restrict__ W1,       // [128,64]
    const float* __restrict__ b1,       // [64]
    const float* __restrict__ W2,       // [64,2]
    const float* __restrict__ b2,       // [2]
    float*       __restrict__ out)      // [B,2]
{
    // flat bin order: 0..5 binary pairs, 6..16 t3, 17..35 t4, 36..66 t5, 67..100 t6
    constexpr int CARD[7] = {2, 2, 2, CARD3, CARD4, CARD5, CARD6};
    constexpr int OFFB[7] = {0, 2, 4, 6, 17, 36, 67};

    __shared__ float w[4][104];
    __shared__ float p[4][128];

    const int tid = threadIdx.x;
    const int g   = tid >> 6;
    const int l   = tid & 63;
    const int sid = blockIdx.x * 4 + g;

    const int   len     = length[sid];
    const float inv_len = 1.0f / (float)len;
    const float inv7    = inv_len * (1.0f / 7.0f);

    const int* s0 = ws_i + (size_t)(sid * 2) * SLOT_STRIDE;
    const int* s1 = s0 + SLOT_STRIDE;
    const bool u2 = (len > 256);

    // hist bins -> weights
    {
        int h0 = s0[l] + (u2 ? s1[l] : 0);
        w[g][6 + l] = (float)h0 * inv7;
        if (l < 31) {
            int h1 = s0[64 + l] + (u2 ? s1[64 + l] : 0);
            w[g][6 + 64 + l] = (float)h1 * inv7;
        }
        if (l < 3) {
            int c1 = s0[95 + l] + (u2 ? s1[95 + l] : 0);
            w[g][2 * l + 1] = (float)c1 * inv7;
            w[g][2 * l]     = (float)(len - c1) * inv7;
        }
        const float* s0f = (const float*)s0;
        const float* s1f = (const float*)s1;
        float c = s0f[104 + l] + (u2 ? s1f[104 + l] : 0.f);
        p[g][64 + l] = c * inv_len;
    }
    __syncthreads();

    // 101-row weighted embedding matvec
    {
        float pc = 0.f;
#pragma unroll
        for (int t = 0; t < 7; ++t) {
            const float* tab = (t == 0) ? e0 : (t == 1) ? e1 : (t == 2) ? e2
                             : (t == 3) ? e3 : (t == 4) ? e4 : (t == 5) ? e5 : e6;
#pragma unroll
            for (int v = 0; v < CARD[t]; ++v) {
                pc = fmaf(w[g][OFFB[t] + v], tab[v * 64 + l], pc);
            }
        }
        p[g][l] = pc;
    }
    __syncthreads();

    // h = relu(pooled @ W1 + b1)
    float acc = b1[l];
#pragma unroll 16
    for (int d = 0; d < 128; ++d) {
        acc = fmaf(p[g][d], W1[d * 64 + l], acc);
    }
    const float h = fmaxf(acc, 0.f);

    // out = relu(h @ W2 + b2), butterfly reduce
    const float2 w2 = ((const float2*)W2)[l];
    float r0 = h * w2.x;
    float r1 = h * w2.y;
#pragma unroll
    for (int off = 1; off <= 32; off <<= 1) {
        r0 += __shfl_xor(r0, off);
        r1 += __shfl_xor(r1, off);
    }
    if (l == 0) {
        const float2 bb2 = *(const float2*)b2;
        float2 res;
        res.x = fmaxf(r0 + bb2.x, 0.f);
        res.y = fmaxf(r1 + bb2.y, 0.f);
        ((float2*)out)[sid] = res;
    }
}

extern "C" void kernel_launch(void* const* d_in, const int* in_sizes, int n_in,
                              void* d_out, int out_size, void* d_ws, size_t ws_size,
                              hipStream_t stream)
{
    const float* cont_x = (const float*)d_in[0];
    const int*   cat_x  = (const int*)d_in[1];
    const int*   length = (const int*)d_in[2];
    const float* e0     = (const float*)d_in[3];
    const float* e1     = (const float*)d_in[4];
    const float* e2     = (const float*)d_in[5];
    const float* e3     = (const float*)d_in[6];
    const float* e4     = (const float*)d_in[7];
    const float* e5     = (const float*)d_in[8];
    const float* e6     = (const float*)d_in[9];
    const float* W_cont = (const float*)d_in[10];
    const float* b_cont = (const float*)d_in[11];
    const float* W1     = (const float*)d_in[12];
    const float* b1     = (const float*)d_in[13];
    const float* W2     = (const float*)d_in[14];
    const float* b2     = (const float*)d_in[15];
    float*       out    = (float*)d_out;

    const int B = in_sizes[2];                 // 2048
    const int S = in_sizes[0] / (B * 5);       // 512

    int* ws_i = (int*)d_ws;                    // 2B slots * 704 B = 2.88 MB

    hipLaunchKernelGGL(pool_tiles, dim3(2 * B), dim3(256), 0, stream,
                       cont_x, cat_x, length, W_cont, b_cont, ws_i, S);

    hipLaunchKernelGGL(head_kernel, dim3(B / 4), dim3(256), 0, stream,
                       ws_i, length,
                       e0, e1, e2, e3, e4, e5, e6,
                       W1, b1, W2, b2, out);
}

// Round 6
// 28.244 us; speedup vs baseline: 1.1434x; 1.1434x over previous
//
#include <hip/hip_runtime.h>
#include <hip/hip_bf16.h>

// Two-kernel MLPRegressor, MFMA cont path:
//  K1 pool_tiles: block = (sample b, half h), 4 waves x one 64-row tile.
//   - hist: 95-bin LDS-atomic histogram (4 big cat tables) + packed binary counts
//   - cont: colsum(relu(X @ W_cont + b)) via mfma_f32_16x16x32_bf16:
//       A = [16 rows x K], K=6 real (x0..x4, bias-aug 1), zero-padded to 32.
//       Real data only in lanes 0-15 (k-group 0); built with 3 bpermutes/tile.
//       B = W'[k][col] (W_cont cols + bias row), built once, lanes 0-15 only.
//       Invalid rows (>= len) get x=0, aug=0 -> relu(0)=0 contribution.
//   Writes partials non-atomically to slot bb=2b+h; K2 skips slot 1 if len<=256.
//  K2 head: wave = sample. Bin weights -> 101-row weighted embedding matvec,
//   cont mean, W1+relu, W2+relu.
//
// Slot layout (stride 176 ints = 704 B):
//   int   [0..94]   hist bins (t3:0-10, t4:11-29, t5:30-60, t6:61-94)
//   int   [95..97]  ones-counts for binary tables 0..2
//   float [104..167] cont ReLU colsums (dims 0..63)

#define CARD3 11
#define CARD4 19
#define CARD5 31
#define CARD6 34
#define SLOT_STRIDE 176

typedef __attribute__((ext_vector_type(8))) short bf16x8;
typedef __attribute__((ext_vector_type(4))) float f32x4;
typedef __attribute__((ext_vector_type(4))) unsigned uintx4;

static __device__ __forceinline__ unsigned pk_bf16(float a, float b) {
    unsigned ua = __float_as_uint(a), ub = __float_as_uint(b);
    ua += 0x7FFFu + ((ua >> 16) & 1u);      // round-to-nearest-even
    ub += 0x7FFFu + ((ub >> 16) & 1u);
    return ((ua >> 16) & 0xFFFFu) | (ub & 0xFFFF0000u);
}

__global__ __launch_bounds__(256) void pool_tiles(
    const float* __restrict__ cont_x,   // [B,S,5]
    const int*   __restrict__ cat_x,    // [B,S,7]
    const int*   __restrict__ length,   // [B]
    const float* __restrict__ W_cont,   // [5,64]
    const float* __restrict__ b_cont,   // [64]
    int*         __restrict__ ws_i,     // slots
    int S)
{
    constexpr int HOFF[4] = {0, 11, 30, 61};

    __shared__ int   hist[4][96];
    __shared__ int   bc_s[4];
    __shared__ float pc[4][64];

    const int bb   = blockIdx.x;
    const int b    = bb >> 1;
    const int half = bb & 1;
    const int len  = length[b];
    if (len <= half * 256) return;

    const int tid = threadIdx.x;
    const int g   = tid >> 6;
    const int l   = tid & 63;
    const int base  = half * 256 + g * 64;
    const int wrows = len - base;          // rows for this wave (may be <= 0)

    // zero own (per-wave private) histogram; same-wave DS ordering suffices
    hist[g][l] = 0;
    if (l < 32) hist[g][64 + l] = 0;

    // ---- B-frags: lanes 0-15 hold W'[j][col = nt*16 + l], j=0..5 real ----
    unsigned bw[4][3];
#pragma unroll
    for (int nt = 0; nt < 4; ++nt) {
        float w0 = 0.f, w1 = 0.f, w2 = 0.f, w3 = 0.f, w4 = 0.f, w5 = 0.f;
        if (l < 16) {
            const int c = nt * 16 + l;
            w0 = W_cont[c];       w1 = W_cont[64 + c];
            w2 = W_cont[128 + c]; w3 = W_cont[192 + c];
            w4 = W_cont[256 + c]; w5 = b_cont[c];
        }
        bw[nt][0] = pk_bf16(w0, w1);
        bw[nt][1] = pk_bf16(w2, w3);
        bw[nt][2] = pk_bf16(w4, w5);
    }
    const uintx4 b0u = {bw[0][0], bw[0][1], bw[0][2], 0u};
    const uintx4 b1u = {bw[1][0], bw[1][1], bw[1][2], 0u};
    const uintx4 b2u = {bw[2][0], bw[2][1], bw[2][2], 0u};
    const uintx4 b3u = {bw[3][0], bw[3][1], bw[3][2], 0u};
    const bf16x8 Bf0 = __builtin_bit_cast(bf16x8, b0u);
    const bf16x8 Bf1 = __builtin_bit_cast(bf16x8, b1u);
    const bf16x8 Bf2 = __builtin_bit_cast(bf16x8, b2u);
    const bf16x8 Bf3 = __builtin_bit_cast(bf16x8, b3u);

    int   c1pack = 0;
    f32x4 sum0 = {0.f, 0.f, 0.f, 0.f};
    f32x4 sum1 = sum0, sum2 = sum0, sum3 = sum0;

    if (wrows > 0) {
        // unconditional stage: row base+l always < S (base <= 448, l <= 63)
        const size_t rowb = (size_t)b * S + base;
        const int*   cp = cat_x  + (rowb + l) * 7;
        const float* xp = cont_x + (rowb + l) * 5;
        const int i0 = cp[0], i1 = cp[1], i2 = cp[2], i3 = cp[3];
        const int i4 = cp[4], i5 = cp[5], i6 = cp[6];
        float x0 = xp[0], x1 = xp[1], x2 = xp[2], x3 = xp[3], x4 = xp[4];

        const bool valid = (l < wrows);
        if (valid) {
            c1pack = i0 + (i1 << 8) + (i2 << 16);
            atomicAdd(&hist[g][HOFF[0] + i3], 1);
            atomicAdd(&hist[g][HOFF[1] + i4], 1);
            atomicAdd(&hist[g][HOFF[2] + i5], 1);
            atomicAdd(&hist[g][HOFF[3] + i6], 1);
        } else {
            x0 = x1 = x2 = x3 = x4 = 0.f;
        }
        const float aug = valid ? 1.0f : 0.0f;
        const unsigned p0 = pk_bf16(x0, x1);
        const unsigned p1 = pk_bf16(x2, x3);
        const unsigned p2 = pk_bf16(x4, aug);

        const int  lo16 = l & 15;
        const bool lo   = (l < 16);
        const f32x4 z = {0.f, 0.f, 0.f, 0.f};

#pragma unroll
        for (int t = 0; t < 4; ++t) {
            const int src = t * 16 + lo16;
            unsigned a0 = (unsigned)__shfl((int)p0, src);
            unsigned a1 = (unsigned)__shfl((int)p1, src);
            unsigned a2 = (unsigned)__shfl((int)p2, src);
            a0 = lo ? a0 : 0u;
            a1 = lo ? a1 : 0u;
            a2 = lo ? a2 : 0u;
            const uintx4 au = {a0, a1, a2, 0u};
            const bf16x8 Af = __builtin_bit_cast(bf16x8, au);

            const f32x4 d0 = __builtin_amdgcn_mfma_f32_16x16x32_bf16(Af, Bf0, z, 0, 0, 0);
            const f32x4 d1 = __builtin_amdgcn_mfma_f32_16x16x32_bf16(Af, Bf1, z, 0, 0, 0);
            const f32x4 d2 = __builtin_amdgcn_mfma_f32_16x16x32_bf16(Af, Bf2, z, 0, 0, 0);
            const f32x4 d3 = __builtin_amdgcn_mfma_f32_16x16x32_bf16(Af, Bf3, z, 0, 0, 0);
#pragma unroll
            for (int i = 0; i < 4; ++i) {
                sum0[i] += fmaxf(d0[i], 0.f);
                sum1[i] += fmaxf(d1[i], 0.f);
                sum2[i] += fmaxf(d2[i], 0.f);
                sum3[i] += fmaxf(d3[i], 0.f);
            }
        }
    }

    // packed binary count reduce (fields < 256)
#pragma unroll
    for (int off = 1; off <= 32; off <<= 1) c1pack += __shfl_xor(c1pack, off);
    if (l == 0) bc_s[g] = c1pack;

    // col sums: sum the 4 row-slots, then reduce across lane-groups (^16, ^32)
    float s0 = sum0[0] + sum0[1] + sum0[2] + sum0[3];
    float s1 = sum1[0] + sum1[1] + sum1[2] + sum1[3];
    float s2 = sum2[0] + sum2[1] + sum2[2] + sum2[3];
    float s3 = sum3[0] + sum3[1] + sum3[2] + sum3[3];
    s0 += __shfl_xor(s0, 16); s0 += __shfl_xor(s0, 32);
    s1 += __shfl_xor(s1, 16); s1 += __shfl_xor(s1, 32);
    s2 += __shfl_xor(s2, 16); s2 += __shfl_xor(s2, 32);
    s3 += __shfl_xor(s3, 16); s3 += __shfl_xor(s3, 32);
    if (l < 16) {
        pc[g][l]      = s0;   // col = nt*16 + l
        pc[g][16 + l] = s1;
        pc[g][32 + l] = s2;
        pc[g][48 + l] = s3;
    }
    __syncthreads();

    int*   slot   = ws_i + (size_t)bb * SLOT_STRIDE;
    float* slot_f = (float*)slot;

    if (tid < 95) {
        slot[tid] = hist[0][tid] + hist[1][tid] + hist[2][tid] + hist[3][tid];
    }
    if (tid >= 96 && tid < 99) {
        const int j = tid - 96;
        const int c1 = ((bc_s[0] >> (8 * j)) & 0xFF) + ((bc_s[1] >> (8 * j)) & 0xFF)
                     + ((bc_s[2] >> (8 * j)) & 0xFF) + ((bc_s[3] >> (8 * j)) & 0xFF);
        slot[95 + j] = c1;
    }
    if (tid >= 128 && tid < 192) {
        const int d = tid - 128;
        slot_f[104 + d] = pc[0][d] + pc[1][d] + pc[2][d] + pc[3][d];
    }
}

__global__ __launch_bounds__(256) void head_kernel(
    const int*   __restrict__ ws_i,
    const int*   __restrict__ length,   // [B]
    const float* __restrict__ e0, const float* __restrict__ e1,
    const float* __restrict__ e2, const float* __restrict__ e3,
    const float* __restrict__ e4, const float* __restrict__ e5,
    const float* __restrict__ e6,
    const float* __restrict__ W1,       // [128,64]
    const float* __restrict__ b1,       // [64]
    const float* __restrict__ W2,       // [64,2]
    const float* __restrict__ b2,       // [2]
    float*       __restrict__ out)      // [B,2]
{
    constexpr int CARD[7] = {2, 2, 2, CARD3, CARD4, CARD5, CARD6};
    constexpr int OFFB[7] = {0, 2, 4, 6, 17, 36, 67};

    __shared__ float w[4][104];
    __shared__ float p[4][128];

    const int tid = threadIdx.x;
    const int g   = tid >> 6;
    const int l   = tid & 63;
    const int sid = blockIdx.x * 4 + g;

    const int   len     = length[sid];
    const float inv_len = 1.0f / (float)len;
    const float inv7    = inv_len * (1.0f / 7.0f);

    const int* s0 = ws_i + (size_t)(sid * 2) * SLOT_STRIDE;
    const int* s1 = s0 + SLOT_STRIDE;
    const bool u2 = (len > 256);

    {
        int h0 = s0[l] + (u2 ? s1[l] : 0);
        w[g][6 + l] = (float)h0 * inv7;
        if (l < 31) {
            int h1 = s0[64 + l] + (u2 ? s1[64 + l] : 0);
            w[g][6 + 64 + l] = (float)h1 * inv7;
        }
        if (l < 3) {
            int c1 = s0[95 + l] + (u2 ? s1[95 + l] : 0);
            w[g][2 * l + 1] = (float)c1 * inv7;
            w[g][2 * l]     = (float)(len - c1) * inv7;
        }
        const float* s0f = (const float*)s0;
        const float* s1f = (const float*)s1;
        float c = s0f[104 + l] + (u2 ? s1f[104 + l] : 0.f);
        p[g][64 + l] = c * inv_len;
    }
    __syncthreads();

    // 101-row weighted embedding matvec
    {
        float pcv = 0.f;
#pragma unroll
        for (int t = 0; t < 7; ++t) {
            const float* tab = (t == 0) ? e0 : (t == 1) ? e1 : (t == 2) ? e2
                             : (t == 3) ? e3 : (t == 4) ? e4 : (t == 5) ? e5 : e6;
#pragma unroll
            for (int v = 0; v < CARD[t]; ++v) {
                pcv = fmaf(w[g][OFFB[t] + v], tab[v * 64 + l], pcv);
            }
        }
        p[g][l] = pcv;
    }
    __syncthreads();

    // h = relu(pooled @ W1 + b1)
    float acc = b1[l];
#pragma unroll 16
    for (int d = 0; d < 128; ++d) {
        acc = fmaf(p[g][d], W1[d * 64 + l], acc);
    }
    const float h = fmaxf(acc, 0.f);

    // out = relu(h @ W2 + b2), butterfly reduce
    const float2 w2 = ((const float2*)W2)[l];
    float r0 = h * w2.x;
    float r1 = h * w2.y;
#pragma unroll
    for (int off = 1; off <= 32; off <<= 1) {
        r0 += __shfl_xor(r0, off);
        r1 += __shfl_xor(r1, off);
    }
    if (l == 0) {
        const float2 bb2 = *(const float2*)b2;
        float2 res;
        res.x = fmaxf(r0 + bb2.x, 0.f);
        res.y = fmaxf(r1 + bb2.y, 0.f);
        ((float2*)out)[sid] = res;
    }
}

extern "C" void kernel_launch(void* const* d_in, const int* in_sizes, int n_in,
                              void* d_out, int out_size, void* d_ws, size_t ws_size,
                              hipStream_t stream)
{
    const float* cont_x = (const float*)d_in[0];
    const int*   cat_x  = (const int*)d_in[1];
    const int*   length = (const int*)d_in[2];
    const float* e0     = (const float*)d_in[3];
    const float* e1     = (const float*)d_in[4];
    const float* e2     = (const float*)d_in[5];
    const float* e3     = (const float*)d_in[6];
    const float* e4     = (const float*)d_in[7];
    const float* e5     = (const float*)d_in[8];
    const float* e6     = (const float*)d_in[9];
    const float* W_cont = (const float*)d_in[10];
    const float* b_cont = (const float*)d_in[11];
    const float* W1     = (const float*)d_in[12];
    const float* b1     = (const float*)d_in[13];
    const float* W2     = (const float*)d_in[14];
    const float* b2     = (const float*)d_in[15];
    float*       out    = (float*)d_out;

    const int B = in_sizes[2];                 // 2048
    const int S = in_sizes[0] / (B * 5);       // 512

    int* ws_i = (int*)d_ws;                    // 2B slots * 704 B = 2.88 MB

    hipLaunchKernelGGL(pool_tiles, dim3(2 * B), dim3(256), 0, stream,
                       cont_x, cat_x, length, W_cont, b_cont, ws_i, S);

    hipLaunchKernelGGL(head_kernel, dim3(B / 4), dim3(256), 0, stream,
                       ws_i, length,
                       e0, e1, e2, e3, e4, e5, e6,
                       W1, b1, W2, b2, out);
}

// Round 7
// 26.595 us; speedup vs baseline: 1.2143x; 1.0620x over previous
//
#include <hip/hip_runtime.h>
#include <hip/hip_bf16.h>

// Single fused kernel: block = sample (2048 blocks x 256 thr = 4 waves).
// Main loop (per wave g, tiles base = g*64, g*64+256):
//   - stage 7 cat ids + 5 cont floats per lane (lane = row)
//   - 95-bin LDS-atomic histogram (4 big tables) + packed binary ones-counts
//   - cont colsum(relu(X@W_cont + b)) via mfma_f32_16x16x32_bf16
//     (K=6 real: x0..x4 + bias-aug 1; lanes 0-15 = k-group 0; zero-padded)
// Epilogue (in-block, LDS):
//   bin weights -> 101-row weighted embedding matvec (bins striped over waves)
//   -> pooled[128] -> W1 (32 dims/wave) -> relu -> W2 butterfly -> out.

#define CARD3 11
#define CARD4 19
#define CARD5 31
#define CARD6 34

typedef __attribute__((ext_vector_type(8))) short bf16x8;
typedef __attribute__((ext_vector_type(4))) float f32x4;
typedef __attribute__((ext_vector_type(4))) unsigned uintx4;

static __device__ __forceinline__ unsigned pk_bf16(float a, float b) {
    unsigned ua = __float_as_uint(a), ub = __float_as_uint(b);
    ua += 0x7FFFu + ((ua >> 16) & 1u);      // round-to-nearest-even
    ub += 0x7FFFu + ((ub >> 16) & 1u);
    return ((ua >> 16) & 0xFFFFu) | (ub & 0xFFFF0000u);
}

__global__ __launch_bounds__(256) void mlp_fused(
    const float* __restrict__ cont_x,   // [B,S,5]
    const int*   __restrict__ cat_x,    // [B,S,7]
    const int*   __restrict__ length,   // [B]
    const float* __restrict__ e0, const float* __restrict__ e1,
    const float* __restrict__ e2, const float* __restrict__ e3,
    const float* __restrict__ e4, const float* __restrict__ e5,
    const float* __restrict__ e6,
    const float* __restrict__ W_cont,   // [5,64]
    const float* __restrict__ b_cont,   // [64]
    const float* __restrict__ W1,       // [128,64]
    const float* __restrict__ b1,       // [64]
    const float* __restrict__ W2,       // [64,2]
    const float* __restrict__ b2,       // [2]
    float*       __restrict__ out,      // [B,2]
    int S)
{
    constexpr int HOFF[4] = {0, 11, 30, 61};
    constexpr int CARD[7] = {2, 2, 2, CARD3, CARD4, CARD5, CARD6};
    constexpr int OFFB[7] = {0, 2, 4, 6, 17, 36, 67};

    __shared__ int   hist[4][96];
    __shared__ int   bc_s[4];
    __shared__ float pcont[4][64];
    __shared__ float w[104];
    __shared__ float p[128];
    __shared__ float pcat[4][64];
    __shared__ float partW1[4][64];

    const int b   = blockIdx.x;
    const int tid = threadIdx.x;
    const int g   = tid >> 6;
    const int l   = tid & 63;
    const int lo16 = l & 15;
    const bool lo  = (l < 16);
    const int len = length[b];

    // zero own wave's private histogram (same-wave DS ordering, no barrier)
    hist[g][l] = 0;
    if (l < 32) hist[g][64 + l] = 0;

    // ---- B-frags via shuffle: each lane loads col l's weights, packs bf16 ----
    unsigned q0, q1, q2;
    {
        const float w0 = W_cont[l],        w1 = W_cont[64 + l];
        const float w2 = W_cont[128 + l],  w3 = W_cont[192 + l];
        const float w4 = W_cont[256 + l],  w5 = b_cont[l];
        q0 = pk_bf16(w0, w1); q1 = pk_bf16(w2, w3); q2 = pk_bf16(w4, w5);
    }
    bf16x8 Bf[4];
#pragma unroll
    for (int nt = 0; nt < 4; ++nt) {
        const int src = nt * 16 + lo16;
        unsigned c0 = (unsigned)__shfl((int)q0, src);
        unsigned c1 = (unsigned)__shfl((int)q1, src);
        unsigned c2 = (unsigned)__shfl((int)q2, src);
        c0 = lo ? c0 : 0u; c1 = lo ? c1 : 0u; c2 = lo ? c2 : 0u;
        const uintx4 bu = {c0, c1, c2, 0u};
        Bf[nt] = __builtin_bit_cast(bf16x8, bu);
    }

    int   c1pack = 0;
    f32x4 sum0 = {0.f, 0.f, 0.f, 0.f};
    f32x4 sum1 = sum0, sum2 = sum0, sum3 = sum0;

    for (int base = g * 64; base < len; base += 256) {
        const int rows = min(64, len - base);

        // unconditional stage: base+l <= 448+63 = 511 < S
        const size_t rowb = (size_t)b * S + base;
        const int*   cp = cat_x  + (rowb + l) * 7;
        const float* xp = cont_x + (rowb + l) * 5;
        const int i0 = cp[0], i1 = cp[1], i2 = cp[2], i3 = cp[3];
        const int i4 = cp[4], i5 = cp[5], i6 = cp[6];
        float x0 = xp[0], x1 = xp[1], x2 = xp[2], x3 = xp[3], x4 = xp[4];

        const bool valid = (l < rows);
        if (valid) {
            c1pack += i0 + (i1 << 8) + (i2 << 16);
            atomicAdd(&hist[g][HOFF[0] + i3], 1);
            atomicAdd(&hist[g][HOFF[1] + i4], 1);
            atomicAdd(&hist[g][HOFF[2] + i5], 1);
            atomicAdd(&hist[g][HOFF[3] + i6], 1);
        } else {
            x0 = x1 = x2 = x3 = x4 = 0.f;
        }
        const float aug = valid ? 1.0f : 0.0f;
        const unsigned p0 = pk_bf16(x0, x1);
        const unsigned p1 = pk_bf16(x2, x3);
        const unsigned p2 = pk_bf16(x4, aug);

        const f32x4 z = {0.f, 0.f, 0.f, 0.f};
#pragma unroll
        for (int t = 0; t < 4; ++t) {
            const int src = t * 16 + lo16;
            unsigned a0 = (unsigned)__shfl((int)p0, src);
            unsigned a1 = (unsigned)__shfl((int)p1, src);
            unsigned a2 = (unsigned)__shfl((int)p2, src);
            a0 = lo ? a0 : 0u; a1 = lo ? a1 : 0u; a2 = lo ? a2 : 0u;
            const uintx4 au = {a0, a1, a2, 0u};
            const bf16x8 Af = __builtin_bit_cast(bf16x8, au);

            const f32x4 d0 = __builtin_amdgcn_mfma_f32_16x16x32_bf16(Af, Bf[0], z, 0, 0, 0);
            const f32x4 d1 = __builtin_amdgcn_mfma_f32_16x16x32_bf16(Af, Bf[1], z, 0, 0, 0);
            const f32x4 d2 = __builtin_amdgcn_mfma_f32_16x16x32_bf16(Af, Bf[2], z, 0, 0, 0);
            const f32x4 d3 = __builtin_amdgcn_mfma_f32_16x16x32_bf16(Af, Bf[3], z, 0, 0, 0);
#pragma unroll
            for (int i = 0; i < 4; ++i) {
                sum0[i] += fmaxf(d0[i], 0.f);
                sum1[i] += fmaxf(d1[i], 0.f);
                sum2[i] += fmaxf(d2[i], 0.f);
                sum3[i] += fmaxf(d3[i], 0.f);
            }
        }
    }

    // packed binary count reduce (fields < 512 per wave after 2 tiles)
#pragma unroll
    for (int off = 1; off <= 32; off <<= 1) c1pack += __shfl_xor(c1pack, off);
    if (l == 0) bc_s[g] = c1pack;

    // cont col sums -> pcont[g][0..63]
    float s0 = sum0[0] + sum0[1] + sum0[2] + sum0[3];
    float s1 = sum1[0] + sum1[1] + sum1[2] + sum1[3];
    float s2 = sum2[0] + sum2[1] + sum2[2] + sum2[3];
    float s3 = sum3[0] + sum3[1] + sum3[2] + sum3[3];
    s0 += __shfl_xor(s0, 16); s0 += __shfl_xor(s0, 32);
    s1 += __shfl_xor(s1, 16); s1 += __shfl_xor(s1, 32);
    s2 += __shfl_xor(s2, 16); s2 += __shfl_xor(s2, 32);
    s3 += __shfl_xor(s3, 16); s3 += __shfl_xor(s3, 32);
    if (lo) {
        pcont[g][l]      = s0;
        pcont[g][16 + l] = s1;
        pcont[g][32 + l] = s2;
        pcont[g][48 + l] = s3;
    }
    __syncthreads();                                   // B1

    const float inv_len = 1.0f / (float)len;
    const float inv7    = inv_len * (1.0f / 7.0f);

    if (tid < 95) {
        const int h = hist[0][tid] + hist[1][tid] + hist[2][tid] + hist[3][tid];
        w[6 + tid] = (float)h * inv7;
    } else if (tid >= 96 && tid < 99) {
        const int j = tid - 96;
        const int c1 = ((bc_s[0] >> (8 * j)) & 0x3FF & 0xFF) + ((bc_s[1] >> (8 * j)) & 0xFF)
                     + ((bc_s[2] >> (8 * j)) & 0xFF) + ((bc_s[3] >> (8 * j)) & 0xFF);
        w[2 * j + 1] = (float)c1 * inv7;
        w[2 * j]     = (float)(len - c1) * inv7;
    }
    if (tid >= 128 && tid < 192) {
        const int d = tid - 128;
        p[64 + d] = (pcont[0][d] + pcont[1][d] + pcont[2][d] + pcont[3][d]) * inv_len;
    }
    __syncthreads();                                   // B2

    // 101-row weighted embedding matvec, bins striped over waves
    {
        float pcv = 0.f;
#pragma unroll
        for (int t = 0; t < 7; ++t) {
            const float* tab = (t == 0) ? e0 : (t == 1) ? e1 : (t == 2) ? e2
                             : (t == 3) ? e3 : (t == 4) ? e4 : (t == 5) ? e5 : e6;
#pragma unroll
            for (int v = 0; v < CARD[t]; ++v) {
                const int i = OFFB[t] + v;             // compile-time
                if ((i & 3) == g) {
                    pcv = fmaf(w[i], tab[v * 64 + l], pcv);
                }
            }
        }
        pcat[g][l] = pcv;
    }
    __syncthreads();                                   // B3

    if (tid < 64) {
        p[tid] = pcat[0][tid] + pcat[1][tid] + pcat[2][tid] + pcat[3][tid];
    }
    __syncthreads();                                   // B4

    // W1: wave g handles input dims [32g, 32g+32)
    {
        float a1 = (g == 0) ? b1[l] : 0.f;
        const int d0 = g * 32;
#pragma unroll 8
        for (int i = 0; i < 32; ++i) {
            const int d = d0 + i;
            a1 = fmaf(p[d], W1[d * 64 + l], a1);
        }
        partW1[g][l] = a1;
    }
    __syncthreads();                                   // B5

    if (tid < 64) {
        const float h = fmaxf(partW1[0][l] + partW1[1][l]
                            + partW1[2][l] + partW1[3][l], 0.f);
        const float2 w2v = ((const float2*)W2)[l];
        float r0 = h * w2v.x;
        float r1 = h * w2v.y;
#pragma unroll
        for (int off = 1; off <= 32; off <<= 1) {
            r0 += __shfl_xor(r0, off);
            r1 += __shfl_xor(r1, off);
        }
        if (l == 0) {
            const float2 bb2 = *(const float2*)b2;
            float2 res;
            res.x = fmaxf(r0 + bb2.x, 0.f);
            res.y = fmaxf(r1 + bb2.y, 0.f);
            ((float2*)out)[b] = res;
        }
    }
}

extern "C" void kernel_launch(void* const* d_in, const int* in_sizes, int n_in,
                              void* d_out, int out_size, void* d_ws, size_t ws_size,
                              hipStream_t stream)
{
    const float* cont_x = (const float*)d_in[0];
    const int*   cat_x  = (const int*)d_in[1];
    const int*   length = (const int*)d_in[2];
    const float* e0     = (const float*)d_in[3];
    const float* e1     = (const float*)d_in[4];
    const float* e2     = (const float*)d_in[5];
    const float* e3     = (const float*)d_in[6];
    const float* e4     = (const float*)d_in[7];
    const float* e5     = (const float*)d_in[8];
    const float* e6     = (const float*)d_in[9];
    const float* W_cont = (const float*)d_in[10];
    const float* b_cont = (const float*)d_in[11];
    const float* W1     = (const float*)d_in[12];
    const float* b1     = (const float*)d_in[13];
    const float* W2     = (const float*)d_in[14];
    const float* b2     = (const float*)d_in[15];
    float*       out    = (float*)d_out;

    const int B = in_sizes[2];                 // 2048
    const int S = in_sizes[0] / (B * 5);       // 512

    hipLaunchKernelGGL(mlp_fused, dim3(B), dim3(256), 0, stream,
                       cont_x, cat_x, length,
                       e0, e1, e2, e3, e4, e5, e6,
                       W_cont, b_cont, W1, b1, W2, b2,
                       out, S);
}

// Round 8
// 26.344 us; speedup vs baseline: 1.2258x; 1.0095x over previous
//
#include <hip/hip_runtime.h>
#include <hip/hip_bf16.h>

// Single fused kernel: block = sample (2048 blocks x 256 thr = 4 waves).
// Wave g owns rows [g*64, g*64+64) and [g*64+256, g*64+320) (2 tiles max).
// All stage loads are len-independent (rows always < S) -> issued straight-line
// at entry, overlapped with B-frag build; len only gates masks/compute.
// Main compute per tile:
//   - 95-bin LDS-atomic histogram (4 big tables) + packed binary ones-counts
//   - cont colsum(relu(X@W_cont + b)) via mfma_f32_16x16x32_bf16
//     (K=6 real: x0..x4 + bias-aug 1; lanes 0-15 = k-group 0; zero-padded)
// Epilogue (3 barriers):
//   B1: hist/bc/pcont ready -> bin weights w[101], cont mean -> LDS
//   B2: waves 0,1 redundantly compute 101-row weighted embedding matvec into
//       registers (lane = dim); W1 stripe per wave (dims 32g..32g+32) fed by
//       intra-wave shfl (g=0,1) or LDS cont-mean (g=2,3)
//   B3: merge W1 partials -> relu -> W2 butterfly -> out.

#define CARD3 11
#define CARD4 19
#define CARD5 31
#define CARD6 34

typedef __attribute__((ext_vector_type(8))) short bf16x8;
typedef __attribute__((ext_vector_type(4))) float f32x4;
typedef __attribute__((ext_vector_type(4))) unsigned uintx4;
typedef int   int4a  __attribute__((ext_vector_type(4), aligned(4)));
typedef int   int2a  __attribute__((ext_vector_type(2), aligned(4)));
typedef float flt4a  __attribute__((ext_vector_type(4), aligned(4)));

static __device__ __forceinline__ unsigned pk_bf16(float a, float b) {
    unsigned ua = __float_as_uint(a), ub = __float_as_uint(b);
    ua += 0x7FFFu + ((ua >> 16) & 1u);      // round-to-nearest-even
    ub += 0x7FFFu + ((ub >> 16) & 1u);
    return ((ua >> 16) & 0xFFFFu) | (ub & 0xFFFF0000u);
}

__global__ __launch_bounds__(256) void mlp_fused(
    const float* __restrict__ cont_x,   // [B,S,5]
    const int*   __restrict__ cat_x,    // [B,S,7]
    const int*   __restrict__ length,   // [B]
    const float* __restrict__ e0, const float* __restrict__ e1,
    const float* __restrict__ e2, const float* __restrict__ e3,
    const float* __restrict__ e4, const float* __restrict__ e5,
    const float* __restrict__ e6,
    const float* __restrict__ W_cont,   // [5,64]
    const float* __restrict__ b_cont,   // [64]
    const float* __restrict__ W1,       // [128,64]
    const float* __restrict__ b1,       // [64]
    const float* __restrict__ W2,       // [64,2]
    const float* __restrict__ b2,       // [2]
    float*       __restrict__ out,      // [B,2]
    int S)
{
    constexpr int HOFF[4] = {0, 11, 30, 61};
    constexpr int CARD[7] = {2, 2, 2, CARD3, CARD4, CARD5, CARD6};
    constexpr int OFFB[7] = {0, 2, 4, 6, 17, 36, 67};

    __shared__ int   hist[4][96];
    __shared__ int   bc_s[4];
    __shared__ float pcont[4][64];
    __shared__ float w[104];
    __shared__ float cmean[64];
    __shared__ float partW1[4][64];

    const int b    = blockIdx.x;
    const int tid  = threadIdx.x;
    const int g    = tid >> 6;
    const int l    = tid & 63;
    const int lo16 = l & 15;
    const bool lo  = (l < 16);

    // ---- issue ALL stage loads now (len-independent addresses) ----
    const size_t r0 = (size_t)b * S + g * 64 + l;
    const size_t r1 = r0 + 256;
    const int4a  ca0 = *(const int4a*)(cat_x + r0 * 7);
    const int2a  cb0 = *(const int2a*)(cat_x + r0 * 7 + 4);
    const int    cc0 = cat_x[r0 * 7 + 6];
    const flt4a  xa0 = *(const flt4a*)(cont_x + r0 * 5);
    const float  xb0 = cont_x[r0 * 5 + 4];
    const int4a  ca1 = *(const int4a*)(cat_x + r1 * 7);
    const int2a  cb1 = *(const int2a*)(cat_x + r1 * 7 + 4);
    const int    cc1 = cat_x[r1 * 7 + 6];
    const flt4a  xa1 = *(const flt4a*)(cont_x + r1 * 5);
    const float  xb1 = cont_x[r1 * 5 + 4];

    const int len = length[b];

    // zero own wave's private histogram (same-wave DS ordering, no barrier)
    hist[g][l] = 0;
    if (l < 32) hist[g][64 + l] = 0;

    // ---- B-frags via shuffle: lane loads col l's weights, packs bf16 ----
    unsigned q0, q1, q2;
    {
        const float w0 = W_cont[l],        w1 = W_cont[64 + l];
        const float w2 = W_cont[128 + l],  w3 = W_cont[192 + l];
        const float w4 = W_cont[256 + l],  w5 = b_cont[l];
        q0 = pk_bf16(w0, w1); q1 = pk_bf16(w2, w3); q2 = pk_bf16(w4, w5);
    }
    bf16x8 Bf[4];
#pragma unroll
    for (int nt = 0; nt < 4; ++nt) {
        const int src = nt * 16 + lo16;
        unsigned c0 = (unsigned)__shfl((int)q0, src);
        unsigned c1 = (unsigned)__shfl((int)q1, src);
        unsigned c2 = (unsigned)__shfl((int)q2, src);
        c0 = lo ? c0 : 0u; c1 = lo ? c1 : 0u; c2 = lo ? c2 : 0u;
        const uintx4 bu = {c0, c1, c2, 0u};
        Bf[nt] = __builtin_bit_cast(bf16x8, bu);
    }

    int   c1pack = 0;
    f32x4 sum0 = {0.f, 0.f, 0.f, 0.f};
    f32x4 sum1 = sum0, sum2 = sum0, sum3 = sum0;
    const f32x4 z = {0.f, 0.f, 0.f, 0.f};

#pragma unroll
    for (int tile = 0; tile < 2; ++tile) {
        const int base = g * 64 + tile * 256;
        if (len <= base) break;                 // wave-uniform

        const int rows = len - base;            // (may exceed 64; mask is l<rows)
        const bool valid = (l < rows);

        const int i0 = tile ? ca1.x : ca0.x, i1 = tile ? ca1.y : ca0.y;
        const int i2 = tile ? ca1.z : ca0.z, i3 = tile ? ca1.w : ca0.w;
        const int i4 = tile ? cb1.x : cb0.x, i5 = tile ? cb1.y : cb0.y;
        const int i6 = tile ? cc1   : cc0;
        float x0 = tile ? xa1.x : xa0.x, x1 = tile ? xa1.y : xa0.y;
        float x2 = tile ? xa1.z : xa0.z, x3 = tile ? xa1.w : xa0.w;
        float x4 = tile ? xb1   : xb0;

        if (valid) {
            c1pack += i0 + (i1 << 8) + (i2 << 16);
            atomicAdd(&hist[g][HOFF[0] + i3], 1);
            atomicAdd(&hist[g][HOFF[1] + i4], 1);
            atomicAdd(&hist[g][HOFF[2] + i5], 1);
            atomicAdd(&hist[g][HOFF[3] + i6], 1);
        } else {
            x0 = x1 = x2 = x3 = x4 = 0.f;
        }
        const float aug = valid ? 1.0f : 0.0f;
        const unsigned p0 = pk_bf16(x0, x1);
        const unsigned p1 = pk_bf16(x2, x3);
        const unsigned p2 = pk_bf16(x4, aug);

#pragma unroll
        for (int t = 0; t < 4; ++t) {
            const int src = t * 16 + lo16;
            unsigned a0 = (unsigned)__shfl((int)p0, src);
            unsigned a1 = (unsigned)__shfl((int)p1, src);
            unsigned a2 = (unsigned)__shfl((int)p2, src);
            a0 = lo ? a0 : 0u; a1 = lo ? a1 : 0u; a2 = lo ? a2 : 0u;
            const uintx4 au = {a0, a1, a2, 0u};
            const bf16x8 Af = __builtin_bit_cast(bf16x8, au);

            const f32x4 d0 = __builtin_amdgcn_mfma_f32_16x16x32_bf16(Af, Bf[0], z, 0, 0, 0);
            const f32x4 d1 = __builtin_amdgcn_mfma_f32_16x16x32_bf16(Af, Bf[1], z, 0, 0, 0);
            const f32x4 d2 = __builtin_amdgcn_mfma_f32_16x16x32_bf16(Af, Bf[2], z, 0, 0, 0);
            const f32x4 d3 = __builtin_amdgcn_mfma_f32_16x16x32_bf16(Af, Bf[3], z, 0, 0, 0);
#pragma unroll
            for (int i = 0; i < 4; ++i) {
                sum0[i] += fmaxf(d0[i], 0.f);
                sum1[i] += fmaxf(d1[i], 0.f);
                sum2[i] += fmaxf(d2[i], 0.f);
                sum3[i] += fmaxf(d3[i], 0.f);
            }
        }
    }

    // packed binary count reduce (fields <= 128 per wave, < 256 ok)
#pragma unroll
    for (int off = 1; off <= 32; off <<= 1) c1pack += __shfl_xor(c1pack, off);
    if (l == 0) bc_s[g] = c1pack;

    // cont col sums -> pcont[g][0..63]
    float s0 = sum0[0] + sum0[1] + sum0[2] + sum0[3];
    float s1 = sum1[0] + sum1[1] + sum1[2] + sum1[3];
    float s2 = sum2[0] + sum2[1] + sum2[2] + sum2[3];
    float s3 = sum3[0] + sum3[1] + sum3[2] + sum3[3];
    s0 += __shfl_xor(s0, 16); s0 += __shfl_xor(s0, 32);
    s1 += __shfl_xor(s1, 16); s1 += __shfl_xor(s1, 32);
    s2 += __shfl_xor(s2, 16); s2 += __shfl_xor(s2, 32);
    s3 += __shfl_xor(s3, 16); s3 += __shfl_xor(s3, 32);
    if (lo) {
        pcont[g][l]      = s0;
        pcont[g][16 + l] = s1;
        pcont[g][32 + l] = s2;
        pcont[g][48 + l] = s3;
    }
    __syncthreads();                                   // B1

    const float inv_len = 1.0f / (float)len;
    const float inv7    = inv_len * (1.0f / 7.0f);

    if (tid < 95) {
        const int h = hist[0][tid] + hist[1][tid] + hist[2][tid] + hist[3][tid];
        w[6 + tid] = (float)h * inv7;
    } else if (tid >= 96 && tid < 99) {
        const int j = tid - 96;
        const int c1 = ((bc_s[0] >> (8 * j)) & 0xFF) + ((bc_s[1] >> (8 * j)) & 0xFF)
                     + ((bc_s[2] >> (8 * j)) & 0xFF) + ((bc_s[3] >> (8 * j)) & 0xFF);
        w[2 * j + 1] = (float)c1 * inv7;
        w[2 * j]     = (float)(len - c1) * inv7;
    }
    if (tid >= 128 && tid < 192) {
        const int d = tid - 128;
        cmean[d] = (pcont[0][d] + pcont[1][d] + pcont[2][d] + pcont[3][d]) * inv_len;
    }
    __syncthreads();                                   // B2

    // waves 0,1: full 101-row weighted embedding matvec into registers
    float pcv = 0.f;
    if (g < 2) {
#pragma unroll
        for (int t = 0; t < 7; ++t) {
            const float* tab = (t == 0) ? e0 : (t == 1) ? e1 : (t == 2) ? e2
                             : (t == 3) ? e3 : (t == 4) ? e4 : (t == 5) ? e5 : e6;
#pragma unroll
            for (int v = 0; v < CARD[t]; ++v) {
                pcv = fmaf(w[OFFB[t] + v], tab[v * 64 + l], pcv);
            }
        }
    }

    // W1: wave g handles input dims [32g, 32g+32)
    {
        float a1 = (g == 0) ? b1[l] : 0.f;
        if (g < 2) {
            const int d0 = g * 32;
#pragma unroll
            for (int i = 0; i < 32; ++i) {
                const int d = d0 + i;
                a1 = fmaf(__shfl(pcv, d), W1[d * 64 + l], a1);   // intra-wave bcast
            }
        } else {
            const int d0 = (g - 2) * 32;
#pragma unroll 8
            for (int i = 0; i < 32; ++i) {
                const int d = d0 + i;
                a1 = fmaf(cmean[d], W1[(64 + d) * 64 + l], a1);
            }
        }
        partW1[g][l] = a1;
    }
    __syncthreads();                                   // B3

    if (tid < 64) {
        const float h = fmaxf(partW1[0][l] + partW1[1][l]
                            + partW1[2][l] + partW1[3][l], 0.f);
        const float2 w2v = ((const float2*)W2)[l];
        float rr0 = h * w2v.x;
        float rr1 = h * w2v.y;
#pragma unroll
        for (int off = 1; off <= 32; off <<= 1) {
            rr0 += __shfl_xor(rr0, off);
            rr1 += __shfl_xor(rr1, off);
        }
        if (l == 0) {
            const float2 bb2 = *(const float2*)b2;
            float2 res;
            res.x = fmaxf(rr0 + bb2.x, 0.f);
            res.y = fmaxf(rr1 + bb2.y, 0.f);
            ((float2*)out)[b] = res;
        }
    }
}

extern "C" void kernel_launch(void* const* d_in, const int* in_sizes, int n_in,
                              void* d_out, int out_size, void* d_ws, size_t ws_size,
                              hipStream_t stream)
{
    const float* cont_x = (const float*)d_in[0];
    const int*   cat_x  = (const int*)d_in[1];
    const int*   length = (const int*)d_in[2];
    const float* e0     = (const float*)d_in[3];
    const float* e1     = (const float*)d_in[4];
    const float* e2     = (const float*)d_in[5];
    const float* e3     = (const float*)d_in[6];
    const float* e4     = (const float*)d_in[7];
    const float* e5     = (const float*)d_in[8];
    const float* e6     = (const float*)d_in[9];
    const float* W_cont = (const float*)d_in[10];
    const float* b_cont = (const float*)d_in[11];
    const float* W1     = (const float*)d_in[12];
    const float* b1     = (const float*)d_in[13];
    const float* W2     = (const float*)d_in[14];
    const float* b2     = (const float*)d_in[15];
    float*       out    = (float*)d_out;

    const int B = in_sizes[2];                 // 2048
    const int S = in_sizes[0] / (B * 5);       // 512

    hipLaunchKernelGGL(mlp_fused, dim3(B), dim3(256), 0, stream,
                       cont_x, cat_x, length,
                       e0, e1, e2, e3, e4, e5, e6,
                       W_cont, b_cont, W1, b1, W2, b2,
                       out, S);
}